// Round 1
// baseline (438.101 us; speedup 1.0000x reference)
//
#include <hip/hip_runtime.h>

// GatedRecurrentCell: pa/pi = x@W^T + b (fp16 MFMA), gates, then chunked linear scan.
// Shapes: B=8 S=2048 D=512 I=2048. M=B*S=16384, N2=2*I=4096, K=D=512.
// ws layout: [0,16MiB) x_f16 | [16,20MiB) Wcat_f16 | [20MiB,..) P (fp32 or fp16) | agg 2MiB | carry 1MiB

#define LOG2_3 1.5849625007211562f

typedef _Float16 f16x8 __attribute__((ext_vector_type(8)));
typedef _Float16 f16x4 __attribute__((ext_vector_type(4)));
typedef float f32x4 __attribute__((ext_vector_type(4)));

__device__ __forceinline__ float sigmoidf_(float v) {
  return 1.0f / (1.0f + __expf(-v));
}

__device__ __forceinline__ void async_copy16(void* lds, const void* gp) {
  __builtin_amdgcn_global_load_lds((__attribute__((address_space(1))) void*)gp,
                                   (__attribute__((address_space(3))) void*)lds,
                                   16, 0, 0);
}

__global__ __launch_bounds__(256) void cvt_f32_to_f16(const float* __restrict__ src,
                                                      _Float16* __restrict__ dst,
                                                      int n4) {
  int idx = blockIdx.x * 256 + threadIdx.x;
  if (idx >= n4) return;
  float4 v = ((const float4*)src)[idx];
  f16x4 h;
  h[0] = (_Float16)v.x;
  h[1] = (_Float16)v.y;
  h[2] = (_Float16)v.z;
  h[3] = (_Float16)v.w;
  ((f16x4*)dst)[idx] = h;
}

// C[m][n] = sum_k A[m][k] * W[n][k] + bias[n];  A:[16384,512] f16, W:[4096,512] f16 (Wa||Wi)
template <typename PT>
__global__ __launch_bounds__(256) void gemm_xw(const _Float16* __restrict__ Ah,
                                               const _Float16* __restrict__ Wh,
                                               const float* __restrict__ ba,
                                               const float* __restrict__ bi,
                                               PT* __restrict__ P) {
  constexpr int K = 512;
  constexpr int N2 = 4096;
  __shared__ __align__(16) _Float16 As[128 * 32];
  __shared__ __align__(16) _Float16 Bs[128 * 32];
  const int t = threadIdx.x;
  const int mBase = blockIdx.y * 128;
  const int nBase = blockIdx.x * 128;
  // staging: thread t loads 16B (8 f16); row r = t/4, col8 = (t%4)*8; second chunk row+64
  const int r = t >> 2;
  const int c8 = (t & 3) * 8;
  const _Float16* gA0 = Ah + (size_t)(mBase + r) * K + c8;
  const _Float16* gB0 = Wh + (size_t)(nBase + r) * K + c8;
  _Float16* lA0 = As + r * 32 + c8;  // byte offset == t*16 (matches lane-contiguous LDS dest)
  _Float16* lB0 = Bs + r * 32 + c8;

  const int lane = t & 63;
  const int wave = t >> 6;
  const int wm = (wave & 1) * 64;
  const int wn = (wave >> 1) * 64;
  const int lrow = lane & 15;
  const int quad = lane >> 4;

  f32x4 acc[4][4];
#pragma unroll
  for (int i = 0; i < 4; ++i)
#pragma unroll
    for (int j = 0; j < 4; ++j)
      acc[i][j] = (f32x4)0.0f;

  for (int kt = 0; kt < K; kt += 32) {
    async_copy16(lA0, gA0 + kt);
    async_copy16(lA0 + 64 * 32, gA0 + (size_t)64 * K + kt);
    async_copy16(lB0, gB0 + kt);
    async_copy16(lB0 + 64 * 32, gB0 + (size_t)64 * K + kt);
    __syncthreads();  // drains vmcnt -> LDS tiles ready
    f16x8 af[4], bf[4];
#pragma unroll
    for (int i = 0; i < 4; ++i)
      af[i] = *(const f16x8*)(As + (wm + i * 16 + lrow) * 32 + quad * 8);
#pragma unroll
    for (int j = 0; j < 4; ++j)
      bf[j] = *(const f16x8*)(Bs + (wn + j * 16 + lrow) * 32 + quad * 8);
#pragma unroll
    for (int i = 0; i < 4; ++i)
#pragma unroll
      for (int j = 0; j < 4; ++j)
        acc[i][j] = __builtin_amdgcn_mfma_f32_16x16x32_f16(af[i], bf[j], acc[i][j], 0, 0, 0);
    __syncthreads();  // all waves done reading before next stage overwrites
  }

  // C/D layout: col = lane&15, row = quad*4 + reg  (m89-verified)
#pragma unroll
  for (int j = 0; j < 4; ++j) {
    const int n = nBase + wn + j * 16 + lrow;
    const float bias = (n < 2048) ? ba[n] : bi[n - 2048];
#pragma unroll
    for (int i = 0; i < 4; ++i) {
#pragma unroll
      for (int rr = 0; rr < 4; ++rr) {
        const int m = mBase + wm + i * 16 + quad * 4 + rr;
        P[(size_t)m * N2 + n] = (PT)(acc[i][j][rr] + bias);
      }
    }
  }
}

// ---- chunked scan: S=2048 = 16 chunks x 128 steps ----
__device__ __forceinline__ void gate_ac(float pa, float pi, float alpha, float& a, float& c) {
  float rg = sigmoidf_(pa);
  a = alpha * exp2f(-LOG2_3 * rg);
  float ig = sigmoidf_(pi);
  c = sqrtf(fmaxf(1.0f - a * a, 0.0f)) * (ig * pi);
}

template <typename PT>
__global__ __launch_bounds__(256) void scan_pass1(const PT* __restrict__ P,
                                                  const float* __restrict__ gate,
                                                  float2* __restrict__ agg) {
  const int i = blockIdx.x * 256 + threadIdx.x;  // 0..2047
  const int ch = blockIdx.y;                     // 0..15
  const int b = blockIdx.z;                      // 0..7
  const float alpha = sigmoidf_(gate[i]);
  const PT* row = P + ((size_t)(b * 2048 + ch * 128)) * 4096 + i;
  float A = 1.0f, H = 0.0f;
  for (int s = 0; s < 128; ++s) {
    float pa = (float)row[0];
    float pi = (float)row[2048];
    row += 4096;
    float a, c;
    gate_ac(pa, pi, alpha, a, c);
    A *= a;
    H = fmaf(a, H, c);
  }
  agg[((size_t)(b * 16 + ch)) * 2048 + i] = make_float2(A, H);
}

__global__ __launch_bounds__(256) void scan_pass2(const float2* __restrict__ agg,
                                                  float* __restrict__ carry) {
  const int i = blockIdx.x * 256 + threadIdx.x;
  const int b = blockIdx.y;
  float h = 0.0f;
  for (int ch = 0; ch < 16; ++ch) {
    size_t o = ((size_t)(b * 16 + ch)) * 2048 + i;
    carry[o] = h;
    float2 aH = agg[o];
    h = fmaf(aH.x, h, aH.y);
  }
}

template <typename PT>
__global__ __launch_bounds__(256) void scan_pass3(const PT* __restrict__ P,
                                                  const float* __restrict__ gate,
                                                  const float* __restrict__ carry,
                                                  float* __restrict__ out) {
  const int i = blockIdx.x * 256 + threadIdx.x;
  const int ch = blockIdx.y;
  const int b = blockIdx.z;
  const float alpha = sigmoidf_(gate[i]);
  float h = carry[((size_t)(b * 16 + ch)) * 2048 + i];
  const PT* row = P + ((size_t)(b * 2048 + ch * 128)) * 4096 + i;
  float* orow = out + ((size_t)(b * 2048 + ch * 128)) * 2048 + i;
  for (int s = 0; s < 128; ++s) {
    float pa = (float)row[0];
    float pi = (float)row[2048];
    row += 4096;
    float a, c;
    gate_ac(pa, pi, alpha, a, c);
    h = fmaf(a, h, c);
    *orow = h;
    orow += 2048;
  }
}

extern "C" void kernel_launch(void* const* d_in, const int* in_sizes, int n_in,
                              void* d_out, int out_size, void* d_ws, size_t ws_size,
                              hipStream_t stream) {
  const float* x = (const float*)d_in[0];
  const float* Wa = (const float*)d_in[1];
  const float* ba = (const float*)d_in[2];
  const float* Wi = (const float*)d_in[3];
  const float* bi = (const float*)d_in[4];
  const float* gate = (const float*)d_in[5];
  float* out = (float*)d_out;

  char* ws = (char*)d_ws;
  _Float16* xh = (_Float16*)ws;                       // 16384*512*2 = 16 MiB
  _Float16* wh = (_Float16*)(ws + 16777216);          // 4096*512*2  = 4 MiB
  char* Pbase = ws + 20971520;
  const size_t MN2 = (size_t)16384 * 4096;

  cvt_f32_to_f16<<<8192, 256, 0, stream>>>(x, xh, 2097152);
  cvt_f32_to_f16<<<1024, 256, 0, stream>>>(Wa, wh, 262144);
  cvt_f32_to_f16<<<1024, 256, 0, stream>>>(Wi, wh + 1048576, 262144);

  const size_t szP32 = MN2 * 4;
  const size_t need32 = 20971520 + szP32 + 2097152 + 1048576;

  if (ws_size >= need32) {
    float* P = (float*)Pbase;
    float2* agg = (float2*)(Pbase + szP32);
    float* carry = (float*)(Pbase + szP32 + 2097152);
    gemm_xw<float><<<dim3(32, 128), 256, 0, stream>>>(xh, wh, ba, bi, P);
    scan_pass1<float><<<dim3(8, 16, 8), 256, 0, stream>>>(P, gate, agg);
    scan_pass2<<<dim3(8, 8), 256, 0, stream>>>(agg, carry);
    scan_pass3<float><<<dim3(8, 16, 8), 256, 0, stream>>>(P, gate, carry, out);
  } else {
    // fp16 P fallback (needs ~151 MiB): slightly more rounding error, still well under threshold
    const size_t szP16 = MN2 * 2;
    _Float16* P = (_Float16*)Pbase;
    float2* agg = (float2*)(Pbase + szP16);
    float* carry = (float*)(Pbase + szP16 + 2097152);
    gemm_xw<_Float16><<<dim3(32, 128), 256, 0, stream>>>(xh, wh, ba, bi, P);
    scan_pass1<_Float16><<<dim3(8, 16, 8), 256, 0, stream>>>(P, gate, agg);
    scan_pass2<<<dim3(8, 8), 256, 0, stream>>>(agg, carry);
    scan_pass3<_Float16><<<dim3(8, 16, 8), 256, 0, stream>>>(P, gate, carry, out);
  }
}

// Round 2
// 432.832 us; speedup vs baseline: 1.0122x; 1.0122x over previous
//
#include <hip/hip_runtime.h>

// GatedRecurrentCell: pa/pi = x@W^T + b (fp16 MFMA), gates, chunked linear scan.
// Shapes: B=8 S=2048 D=512 I=2048. M=B*S=16384, N2=2*I=4096, K=D=512.
// R2: P stored fp16 (halves P traffic, error self-regularized), half2-vectorized
// scan passes, single cvt launch.
// ws layout: [0,16MiB) x_f16 | [16,20MiB) W_f16 | [20MiB,+128MiB) P f16 | agg 2MiB | carry 1MiB

#define LOG2_3 1.5849625007211562f

typedef _Float16 f16x8 __attribute__((ext_vector_type(8)));
typedef _Float16 f16x4 __attribute__((ext_vector_type(4)));
typedef _Float16 f16x2 __attribute__((ext_vector_type(2)));
typedef float f32x4 __attribute__((ext_vector_type(4)));

__device__ __forceinline__ float sigmoidf_(float v) {
  return 1.0f / (1.0f + __expf(-v));
}

__device__ __forceinline__ void async_copy16(void* lds, const void* gp) {
  __builtin_amdgcn_global_load_lds((__attribute__((address_space(1))) void*)gp,
                                   (__attribute__((address_space(3))) void*)lds,
                                   16, 0, 0);
}

// One launch converts x (2097152 float4s), Wa (262144), Wi (262144) to fp16.
__global__ __launch_bounds__(256) void cvt_all(const float* __restrict__ x,
                                               const float* __restrict__ Wa,
                                               const float* __restrict__ Wi,
                                               _Float16* __restrict__ xh,
                                               _Float16* __restrict__ wh) {
  int idx = blockIdx.x * 256 + threadIdx.x;
  const float* src;
  _Float16* dst;
  int off;
  if (idx < 2097152) {
    src = x; dst = xh; off = idx;
  } else if (idx < 2097152 + 262144) {
    src = Wa; dst = wh; off = idx - 2097152;
  } else {
    src = Wi; dst = wh + 1048576; off = idx - 2359296;
  }
  float4 v = ((const float4*)src)[off];
  f16x4 h;
  h[0] = (_Float16)v.x;
  h[1] = (_Float16)v.y;
  h[2] = (_Float16)v.z;
  h[3] = (_Float16)v.w;
  ((f16x4*)dst)[off] = h;
}

// P[m][n] = sum_k A[m][k] * W[n][k] + bias[n];  A:[16384,512] f16, W:[4096,512] f16 (Wa||Wi)
__global__ __launch_bounds__(256) void gemm_xw(const _Float16* __restrict__ Ah,
                                               const _Float16* __restrict__ Wh,
                                               const float* __restrict__ ba,
                                               const float* __restrict__ bi,
                                               _Float16* __restrict__ P) {
  constexpr int K = 512;
  constexpr int N2 = 4096;
  __shared__ __align__(16) _Float16 As[128 * 32];
  __shared__ __align__(16) _Float16 Bs[128 * 32];
  const int t = threadIdx.x;
  const int mBase = blockIdx.y * 128;
  const int nBase = blockIdx.x * 128;
  const int r = t >> 2;
  const int c8 = (t & 3) * 8;
  const _Float16* gA0 = Ah + (size_t)(mBase + r) * K + c8;
  const _Float16* gB0 = Wh + (size_t)(nBase + r) * K + c8;
  _Float16* lA0 = As + r * 32 + c8;  // byte offset == t*16 (lane-contiguous LDS dest)
  _Float16* lB0 = Bs + r * 32 + c8;

  const int lane = t & 63;
  const int wave = t >> 6;
  const int wm = (wave & 1) * 64;
  const int wn = (wave >> 1) * 64;
  const int lrow = lane & 15;
  const int quad = lane >> 4;

  f32x4 acc[4][4];
#pragma unroll
  for (int i = 0; i < 4; ++i)
#pragma unroll
    for (int j = 0; j < 4; ++j)
      acc[i][j] = (f32x4)0.0f;

  for (int kt = 0; kt < K; kt += 32) {
    async_copy16(lA0, gA0 + kt);
    async_copy16(lA0 + 64 * 32, gA0 + (size_t)64 * K + kt);
    async_copy16(lB0, gB0 + kt);
    async_copy16(lB0 + 64 * 32, gB0 + (size_t)64 * K + kt);
    __syncthreads();
    f16x8 af[4], bf[4];
#pragma unroll
    for (int i = 0; i < 4; ++i)
      af[i] = *(const f16x8*)(As + (wm + i * 16 + lrow) * 32 + quad * 8);
#pragma unroll
    for (int j = 0; j < 4; ++j)
      bf[j] = *(const f16x8*)(Bs + (wn + j * 16 + lrow) * 32 + quad * 8);
#pragma unroll
    for (int i = 0; i < 4; ++i)
#pragma unroll
      for (int j = 0; j < 4; ++j)
        acc[i][j] = __builtin_amdgcn_mfma_f32_16x16x32_f16(af[i], bf[j], acc[i][j], 0, 0, 0);
    __syncthreads();
  }

  // C/D layout: col = lane&15, row = quad*4 + reg  (m89-verified)
#pragma unroll
  for (int j = 0; j < 4; ++j) {
    const int n = nBase + wn + j * 16 + lrow;
    const float bias = (n < 2048) ? ba[n] : bi[n - 2048];
#pragma unroll
    for (int i = 0; i < 4; ++i) {
#pragma unroll
      for (int rr = 0; rr < 4; ++rr) {
        const int m = mBase + wm + i * 16 + quad * 4 + rr;
        P[(size_t)m * N2 + n] = (_Float16)(acc[i][j][rr] + bias);
      }
    }
  }
}

// ---- chunked scan: S=2048 = 16 chunks x 128 steps; 2 i-lanes per thread ----
__device__ __forceinline__ void gate_ac(float pa, float pi, float alpha, float& a, float& c) {
  float rg = sigmoidf_(pa);
  a = alpha * exp2f(-LOG2_3 * rg);
  float ig = sigmoidf_(pi);
  c = sqrtf(fmaxf(1.0f - a * a, 0.0f)) * (ig * pi);
}

__global__ __launch_bounds__(256) void scan_pass1(const _Float16* __restrict__ P,
                                                  const float* __restrict__ gate,
                                                  float2* __restrict__ agg) {
  const int tt = blockIdx.x * 256 + threadIdx.x;  // 0..1023
  const int i0 = tt * 2;
  const int ch = blockIdx.y;  // 0..15
  const int b = blockIdx.z;   // 0..7
  const float2 g = ((const float2*)gate)[tt];
  const float al0 = sigmoidf_(g.x);
  const float al1 = sigmoidf_(g.y);
  const _Float16* row = P + ((size_t)(b * 2048 + ch * 128)) * 4096 + i0;
  float A0 = 1.0f, H0 = 0.0f, A1 = 1.0f, H1 = 0.0f;
  for (int s = 0; s < 128; ++s) {
    f16x2 pa2 = *(const f16x2*)(row);
    f16x2 pi2 = *(const f16x2*)(row + 2048);
    row += 4096;
    float a, c;
    gate_ac((float)pa2[0], (float)pi2[0], al0, a, c);
    A0 *= a;
    H0 = fmaf(a, H0, c);
    gate_ac((float)pa2[1], (float)pi2[1], al1, a, c);
    A1 *= a;
    H1 = fmaf(a, H1, c);
  }
  float4 o;
  o.x = A0; o.y = H0; o.z = A1; o.w = H1;
  ((float4*)agg)[((size_t)(b * 16 + ch)) * 1024 + tt] = o;
}

__global__ __launch_bounds__(256) void scan_pass2(const float2* __restrict__ agg,
                                                  float* __restrict__ carry) {
  const int i = blockIdx.x * 256 + threadIdx.x;  // 0..2047
  const int b = blockIdx.y;
  float h = 0.0f;
  for (int ch = 0; ch < 16; ++ch) {
    size_t o = ((size_t)(b * 16 + ch)) * 2048 + i;
    carry[o] = h;
    float2 aH = agg[o];
    h = fmaf(aH.x, h, aH.y);
  }
}

__global__ __launch_bounds__(256) void scan_pass3(const _Float16* __restrict__ P,
                                                  const float* __restrict__ gate,
                                                  const float* __restrict__ carry,
                                                  float* __restrict__ out) {
  const int tt = blockIdx.x * 256 + threadIdx.x;  // 0..1023
  const int i0 = tt * 2;
  const int ch = blockIdx.y;
  const int b = blockIdx.z;
  const float2 g = ((const float2*)gate)[tt];
  const float al0 = sigmoidf_(g.x);
  const float al1 = sigmoidf_(g.y);
  const float2 cr = ((const float2*)(carry + ((size_t)(b * 16 + ch)) * 2048))[tt];
  float h0 = cr.x, h1 = cr.y;
  const _Float16* row = P + ((size_t)(b * 2048 + ch * 128)) * 4096 + i0;
  float* orow = out + ((size_t)(b * 2048 + ch * 128)) * 2048 + i0;
  for (int s = 0; s < 128; ++s) {
    f16x2 pa2 = *(const f16x2*)(row);
    f16x2 pi2 = *(const f16x2*)(row + 2048);
    row += 4096;
    float a, c;
    gate_ac((float)pa2[0], (float)pi2[0], al0, a, c);
    h0 = fmaf(a, h0, c);
    gate_ac((float)pa2[1], (float)pi2[1], al1, a, c);
    h1 = fmaf(a, h1, c);
    float2 o;
    o.x = h0; o.y = h1;
    *(float2*)orow = o;
    orow += 2048;
  }
}

extern "C" void kernel_launch(void* const* d_in, const int* in_sizes, int n_in,
                              void* d_out, int out_size, void* d_ws, size_t ws_size,
                              hipStream_t stream) {
  const float* x = (const float*)d_in[0];
  const float* Wa = (const float*)d_in[1];
  const float* ba = (const float*)d_in[2];
  const float* Wi = (const float*)d_in[3];
  const float* bi = (const float*)d_in[4];
  const float* gate = (const float*)d_in[5];
  float* out = (float*)d_out;

  char* ws = (char*)d_ws;
  _Float16* xh = (_Float16*)ws;              // 16 MiB
  _Float16* wh = (_Float16*)(ws + 16777216); // 4 MiB
  const size_t MN2 = (size_t)16384 * 4096;
  _Float16* P = (_Float16*)(ws + 20971520);  // 128 MiB fp16
  float2* agg = (float2*)(ws + 20971520 + MN2 * 2);
  float* carry = (float*)(ws + 20971520 + MN2 * 2 + 2097152);

  cvt_all<<<10240, 256, 0, stream>>>(x, Wa, Wi, xh, wh);
  gemm_xw<<<dim3(32, 128), 256, 0, stream>>>(xh, wh, ba, bi, P);
  scan_pass1<<<dim3(4, 16, 8), 256, 0, stream>>>(P, gate, agg);
  scan_pass2<<<dim3(8, 8), 256, 0, stream>>>(agg, carry);
  scan_pass3<<<dim3(4, 16, 8), 256, 0, stream>>>(P, gate, carry, out);
}

// Round 3
// 378.712 us; speedup vs baseline: 1.1568x; 1.1429x over previous
//
#include <hip/hip_runtime.h>

// GatedRecurrentCell: pa/pi = x@W^T + b (fp16 MFMA), gates, chunked linear scan.
// Shapes: B=8 S=2048 D=512 I=2048. M=B*S=16384, N2=2*I=4096, K=D=512.
// R3: 64 chunks x 32 steps (32 waves/CU in scan passes), unrolled batched loads,
// GEMM epilogue coalesced via LDS transpose.
// ws: [0,16Mi) x_f16 | [16,20Mi) W_f16 | [20Mi,+128Mi) P f16 | +8Mi agg | +4Mi carry

#define LOG2_3 1.5849625007211562f

typedef _Float16 f16x8 __attribute__((ext_vector_type(8)));
typedef _Float16 f16x4 __attribute__((ext_vector_type(4)));
typedef _Float16 f16x2 __attribute__((ext_vector_type(2)));
typedef float f32x4 __attribute__((ext_vector_type(4)));

__device__ __forceinline__ float sigmoidf_(float v) {
  return 1.0f / (1.0f + __expf(-v));
}

__device__ __forceinline__ void async_copy16(void* lds, const void* gp) {
  __builtin_amdgcn_global_load_lds((__attribute__((address_space(1))) void*)gp,
                                   (__attribute__((address_space(3))) void*)lds,
                                   16, 0, 0);
}

__global__ __launch_bounds__(256) void cvt_all(const float* __restrict__ x,
                                               const float* __restrict__ Wa,
                                               const float* __restrict__ Wi,
                                               _Float16* __restrict__ xh,
                                               _Float16* __restrict__ wh) {
  int idx = blockIdx.x * 256 + threadIdx.x;
  const float* src;
  _Float16* dst;
  int off;
  if (idx < 2097152) {
    src = x; dst = xh; off = idx;
  } else if (idx < 2097152 + 262144) {
    src = Wa; dst = wh; off = idx - 2097152;
  } else {
    src = Wi; dst = wh + 1048576; off = idx - 2359296;
  }
  float4 v = ((const float4*)src)[off];
  f16x4 h;
  h[0] = (_Float16)v.x;
  h[1] = (_Float16)v.y;
  h[2] = (_Float16)v.z;
  h[3] = (_Float16)v.w;
  ((f16x4*)dst)[off] = h;
}

// P[m][n] = sum_k A[m][k]*W[n][k] + bias[n]; A:[16384,512] f16, W:[4096,512] f16 (Wa||Wi)
__global__ __launch_bounds__(256) void gemm_xw(const _Float16* __restrict__ Ah,
                                               const _Float16* __restrict__ Wh,
                                               const float* __restrict__ ba,
                                               const float* __restrict__ bi,
                                               _Float16* __restrict__ P) {
  constexpr int K = 512;
  constexpr int N2 = 4096;
  // K-loop: As=smem[0,4096), Bs=smem[4096,8192). Epilogue: stg rows of 136 (64x136=8704).
  __shared__ __align__(16) _Float16 smem[8704];
  _Float16* As = smem;
  _Float16* Bs = smem + 4096;
  const int t = threadIdx.x;
  const int mBase = blockIdx.y * 128;
  const int nBase = blockIdx.x * 128;
  const int r = t >> 2;
  const int c8 = (t & 3) * 8;
  const _Float16* gA0 = Ah + (size_t)(mBase + r) * K + c8;
  const _Float16* gB0 = Wh + (size_t)(nBase + r) * K + c8;
  _Float16* lA0 = As + r * 32 + c8;  // byte offset == t*16 (lane-contiguous LDS dest)
  _Float16* lB0 = Bs + r * 32 + c8;

  const int lane = t & 63;
  const int wave = t >> 6;
  const int wm = (wave & 1) * 64;
  const int wn = (wave >> 1) * 64;
  const int lrow = lane & 15;
  const int quad = lane >> 4;

  f32x4 acc[4][4];
#pragma unroll
  for (int i = 0; i < 4; ++i)
#pragma unroll
    for (int j = 0; j < 4; ++j)
      acc[i][j] = (f32x4)0.0f;

  for (int kt = 0; kt < K; kt += 32) {
    async_copy16(lA0, gA0 + kt);
    async_copy16(lA0 + 64 * 32, gA0 + (size_t)64 * K + kt);
    async_copy16(lB0, gB0 + kt);
    async_copy16(lB0 + 64 * 32, gB0 + (size_t)64 * K + kt);
    __syncthreads();
    f16x8 af[4], bf[4];
#pragma unroll
    for (int i = 0; i < 4; ++i)
      af[i] = *(const f16x8*)(As + (wm + i * 16 + lrow) * 32 + quad * 8);
#pragma unroll
    for (int j = 0; j < 4; ++j)
      bf[j] = *(const f16x8*)(Bs + (wn + j * 16 + lrow) * 32 + quad * 8);
#pragma unroll
    for (int i = 0; i < 4; ++i)
#pragma unroll
      for (int j = 0; j < 4; ++j)
        acc[i][j] = __builtin_amdgcn_mfma_f32_16x16x32_f16(af[i], bf[j], acc[i][j], 0, 0, 0);
    __syncthreads();
  }

  // bias per j (n = nBase + wn + j*16 + lrow)
  float bias[4];
#pragma unroll
  for (int j = 0; j < 4; ++j) {
    const int n = nBase + wn + j * 16 + lrow;
    bias[j] = (n < 2048) ? ba[n] : bi[n - 2048];
  }

  // Epilogue: 2 rounds of 64 m-rows staged via LDS, stored coalesced.
  // C/D layout: col = lane&15, row = quad*4 + reg (m89-verified)
  const int row_r = t >> 4;        // 0..15
  const int col8 = (t & 15) * 8;   // 0..120
#pragma unroll
  for (int h = 0; h < 2; ++h) {
    if (wm == h * 64) {
#pragma unroll
      for (int i = 0; i < 4; ++i)
#pragma unroll
        for (int j = 0; j < 4; ++j)
#pragma unroll
          for (int rr = 0; rr < 4; ++rr)
            smem[(i * 16 + quad * 4 + rr) * 136 + wn + j * 16 + lrow] =
                (_Float16)(acc[i][j][rr] + bias[j]);
    }
    __syncthreads();
#pragma unroll
    for (int it = 0; it < 4; ++it) {
      const int m_loc = it * 16 + row_r;
      f16x8 v = *(const f16x8*)(smem + m_loc * 136 + col8);
      *(f16x8*)(P + (size_t)(mBase + h * 64 + m_loc) * N2 + nBase + col8) = v;
    }
    __syncthreads();
  }
}

// ---- chunked scan: S=2048 = 64 chunks x 32 steps; 2 i-lanes per thread ----
__device__ __forceinline__ void gate_ac(float pa, float pi, float alpha, float& a, float& c) {
  float rg = sigmoidf_(pa);
  a = alpha * exp2f(-LOG2_3 * rg);
  float ig = sigmoidf_(pi);
  c = sqrtf(fmaxf(1.0f - a * a, 0.0f)) * (ig * pi);
}

__global__ __launch_bounds__(256) void scan_pass1(const _Float16* __restrict__ P,
                                                  const float* __restrict__ gate,
                                                  float2* __restrict__ agg) {
  const int tt = blockIdx.x * 256 + threadIdx.x;  // 0..1023
  const int i0 = tt * 2;
  const int ch = blockIdx.y;  // 0..63
  const int b = blockIdx.z;   // 0..7
  const float2 g = ((const float2*)gate)[tt];
  const float al0 = sigmoidf_(g.x);
  const float al1 = sigmoidf_(g.y);
  const _Float16* row = P + ((size_t)(b * 2048 + ch * 32)) * 4096 + i0;
  float A0 = 1.0f, H0 = 0.0f, A1 = 1.0f, H1 = 0.0f;
  for (int s4 = 0; s4 < 8; ++s4) {
    f16x2 pa2[4], pi2[4];
#pragma unroll
    for (int u = 0; u < 4; ++u) {
      pa2[u] = *(const f16x2*)(row + (size_t)u * 4096);
      pi2[u] = *(const f16x2*)(row + (size_t)u * 4096 + 2048);
    }
    row += 4 * 4096;
#pragma unroll
    for (int u = 0; u < 4; ++u) {
      float a, c;
      gate_ac((float)pa2[u][0], (float)pi2[u][0], al0, a, c);
      A0 *= a;
      H0 = fmaf(a, H0, c);
      gate_ac((float)pa2[u][1], (float)pi2[u][1], al1, a, c);
      A1 *= a;
      H1 = fmaf(a, H1, c);
    }
  }
  float4 o;
  o.x = A0; o.y = H0; o.z = A1; o.w = H1;
  ((float4*)agg)[((size_t)(b * 64 + ch)) * 1024 + tt] = o;
}

__global__ __launch_bounds__(64) void scan_pass2(const float2* __restrict__ agg,
                                                 float* __restrict__ carry) {
  const int i = blockIdx.x * 64 + threadIdx.x;  // grid.x=32 -> 0..2047
  const int b = blockIdx.y;
  float h = 0.0f;
  for (int c8 = 0; c8 < 8; ++c8) {
    float2 aH[8];
#pragma unroll
    for (int u = 0; u < 8; ++u)
      aH[u] = agg[((size_t)(b * 64 + c8 * 8 + u)) * 2048 + i];
#pragma unroll
    for (int u = 0; u < 8; ++u) {
      carry[((size_t)(b * 64 + c8 * 8 + u)) * 2048 + i] = h;
      h = fmaf(aH[u].x, h, aH[u].y);
    }
  }
}

__global__ __launch_bounds__(256) void scan_pass3(const _Float16* __restrict__ P,
                                                  const float* __restrict__ gate,
                                                  const float* __restrict__ carry,
                                                  float* __restrict__ out) {
  const int tt = blockIdx.x * 256 + threadIdx.x;  // 0..1023
  const int i0 = tt * 2;
  const int ch = blockIdx.y;  // 0..63
  const int b = blockIdx.z;
  const float2 g = ((const float2*)gate)[tt];
  const float al0 = sigmoidf_(g.x);
  const float al1 = sigmoidf_(g.y);
  const float2 cr = ((const float2*)(carry + ((size_t)(b * 64 + ch)) * 2048))[tt];
  float h0 = cr.x, h1 = cr.y;
  const _Float16* row = P + ((size_t)(b * 2048 + ch * 32)) * 4096 + i0;
  float* orow = out + ((size_t)(b * 2048 + ch * 32)) * 2048 + i0;
  for (int s4 = 0; s4 < 8; ++s4) {
    f16x2 pa2[4], pi2[4];
#pragma unroll
    for (int u = 0; u < 4; ++u) {
      pa2[u] = *(const f16x2*)(row + (size_t)u * 4096);
      pi2[u] = *(const f16x2*)(row + (size_t)u * 4096 + 2048);
    }
    row += 4 * 4096;
#pragma unroll
    for (int u = 0; u < 4; ++u) {
      float a, c;
      gate_ac((float)pa2[u][0], (float)pi2[u][0], al0, a, c);
      h0 = fmaf(a, h0, c);
      gate_ac((float)pa2[u][1], (float)pi2[u][1], al1, a, c);
      h1 = fmaf(a, h1, c);
      float2 o;
      o.x = h0; o.y = h1;
      *(float2*)(orow + (size_t)u * 2048) = o;
    }
    orow += 4 * 2048;
  }
}

extern "C" void kernel_launch(void* const* d_in, const int* in_sizes, int n_in,
                              void* d_out, int out_size, void* d_ws, size_t ws_size,
                              hipStream_t stream) {
  const float* x = (const float*)d_in[0];
  const float* Wa = (const float*)d_in[1];
  const float* ba = (const float*)d_in[2];
  const float* Wi = (const float*)d_in[3];
  const float* bi = (const float*)d_in[4];
  const float* gate = (const float*)d_in[5];
  float* out = (float*)d_out;

  char* ws = (char*)d_ws;
  _Float16* xh = (_Float16*)ws;               // 16 MiB
  _Float16* wh = (_Float16*)(ws + 16777216);  // 4 MiB
  const size_t MN2 = (size_t)16384 * 4096;
  _Float16* P = (_Float16*)(ws + 20971520);   // 128 MiB fp16
  float2* agg = (float2*)(ws + 20971520 + MN2 * 2);            // 8 MiB
  float* carry = (float*)(ws + 20971520 + MN2 * 2 + 8388608);  // 4 MiB

  cvt_all<<<10240, 256, 0, stream>>>(x, Wa, Wi, xh, wh);
  gemm_xw<<<dim3(32, 128), 256, 0, stream>>>(xh, wh, ba, bi, P);
  scan_pass1<<<dim3(4, 64, 8), 256, 0, stream>>>(P, gate, agg);
  scan_pass2<<<dim3(32, 8), 64, 0, stream>>>(agg, carry);
  scan_pass3<<<dim3(4, 64, 8), 256, 0, stream>>>(P, gate, carry, out);
}

// Round 4
// 356.906 us; speedup vs baseline: 1.2275x; 1.0611x over previous
//
#include <hip/hip_runtime.h>

// GatedRecurrentCell: pa/pi = x@W^T + b (fp16 MFMA) with gates FUSED into the
// GEMM epilogue; (a,c) stored fp16; chunked linear scan (64 chunks x 32 steps).
// Shapes: B=8 S=2048 D=512 I=2048. M=B*S=16384, N2=2*I=4096, K=D=512.
// W layout: interleaved rows (2i=Wa_i, 2i+1=Wi_i) so each n-tile holds (pa,pi)
// pairs for 64 i's -> epilogue computes a,c + 32-step chunk aggregates in-block.
// ws: [0,16Mi) x_f16 | [16,20Mi) W_f16 | [20Mi,+128Mi) AC f16 | +8Mi agg | +4Mi carry

#define LOG2_3 1.5849625007211562f

typedef _Float16 f16x8 __attribute__((ext_vector_type(8)));
typedef _Float16 f16x4 __attribute__((ext_vector_type(4)));
typedef _Float16 f16x2 __attribute__((ext_vector_type(2)));
typedef float f32x4 __attribute__((ext_vector_type(4)));

__device__ __forceinline__ float sigmoidf_(float v) {
  return 1.0f / (1.0f + __expf(-v));
}

__device__ __forceinline__ void async_copy16(void* lds, const void* gp) {
  __builtin_amdgcn_global_load_lds((__attribute__((address_space(1))) void*)gp,
                                   (__attribute__((address_space(3))) void*)lds,
                                   16, 0, 0);
}

// x -> xh (plain). Wa/Wi -> wh with row interleave: wh row 2i = Wa_i, 2i+1 = Wi_i.
__global__ __launch_bounds__(256) void cvt_all(const float* __restrict__ x,
                                               const float* __restrict__ Wa,
                                               const float* __restrict__ Wi,
                                               _Float16* __restrict__ xh,
                                               _Float16* __restrict__ wh) {
  int idx = blockIdx.x * 256 + threadIdx.x;
  const float* src;
  _Float16* dst;
  int off, doff;
  if (idx < 2097152) {
    src = x; dst = xh; off = idx; doff = idx;
  } else if (idx < 2097152 + 262144) {
    src = Wa; dst = wh; off = idx - 2097152;
    doff = off + ((off >> 7) << 7);          // (2i)*128 + k4
  } else {
    src = Wi; dst = wh; off = idx - 2359296;
    doff = off + ((off >> 7) << 7) + 128;    // (2i+1)*128 + k4
  }
  float4 v = ((const float4*)src)[off];
  f16x4 h;
  h[0] = (_Float16)v.x;
  h[1] = (_Float16)v.y;
  h[2] = (_Float16)v.z;
  h[3] = (_Float16)v.w;
  ((f16x4*)dst)[doff] = h;
}

__device__ __forceinline__ void gate_ac(float pa, float pi, float alpha, float& a, float& c) {
  float rg = sigmoidf_(pa);
  a = alpha * exp2f(-LOG2_3 * rg);
  float ig = sigmoidf_(pi);
  c = sqrtf(fmaxf(1.0f - a * a, 0.0f)) * (ig * pi);
}

// GEMM 128x128 tile + fused gate epilogue.
// AC[m][2i..2i+1] = (a,c) fp16. agg[(b*64+ch)][i] = (A,H) over 32-step chunk.
__global__ __launch_bounds__(256) void gemm_gate(const _Float16* __restrict__ Ah,
                                                 const _Float16* __restrict__ Wh,
                                                 const float* __restrict__ ba,
                                                 const float* __restrict__ bi,
                                                 const float* __restrict__ gate,
                                                 _Float16* __restrict__ AC,
                                                 float2* __restrict__ agg) {
  constexpr int K = 512;
  constexpr int N2 = 4096;
  __shared__ __align__(16) _Float16 smem[8704];  // K-loop: As[0,4096) Bs[4096,8192); epi: 64x136
  __shared__ float pAs[8 * 65];                  // partials, padded stride 65 (conflict-free)
  __shared__ float pHs[8 * 65];
  _Float16* As = smem;
  _Float16* Bs = smem + 4096;
  const int t = threadIdx.x;
  const int mBase = blockIdx.y * 128;
  const int nBase = blockIdx.x * 128;
  const int r = t >> 2;
  const int c8 = (t & 3) * 8;
  const _Float16* gA0 = Ah + (size_t)(mBase + r) * K + c8;
  const _Float16* gB0 = Wh + (size_t)(nBase + r) * K + c8;
  _Float16* lA0 = As + r * 32 + c8;  // byte offset == t*16 (lane-contiguous LDS dest)
  _Float16* lB0 = Bs + r * 32 + c8;

  const int lane = t & 63;
  const int wave = t >> 6;
  const int wm = (wave & 1) * 64;
  const int wn = (wave >> 1) * 64;
  const int lrow = lane & 15;
  const int quad = lane >> 4;

  f32x4 acc[4][4];
#pragma unroll
  for (int i = 0; i < 4; ++i)
#pragma unroll
    for (int j = 0; j < 4; ++j)
      acc[i][j] = (f32x4)0.0f;

  for (int kt = 0; kt < K; kt += 32) {
    async_copy16(lA0, gA0 + kt);
    async_copy16(lA0 + 64 * 32, gA0 + (size_t)64 * K + kt);
    async_copy16(lB0, gB0 + kt);
    async_copy16(lB0 + 64 * 32, gB0 + (size_t)64 * K + kt);
    __syncthreads();
    f16x8 af[4], bf[4];
#pragma unroll
    for (int i = 0; i < 4; ++i)
      af[i] = *(const f16x8*)(As + (wm + i * 16 + lrow) * 32 + quad * 8);
#pragma unroll
    for (int j = 0; j < 4; ++j)
      bf[j] = *(const f16x8*)(Bs + (wn + j * 16 + lrow) * 32 + quad * 8);
#pragma unroll
    for (int i = 0; i < 4; ++i)
#pragma unroll
      for (int j = 0; j < 4; ++j)
        acc[i][j] = __builtin_amdgcn_mfma_f32_16x16x32_f16(af[i], bf[j], acc[i][j], 0, 0, 0);
    __syncthreads();
  }

  // bias: col n even -> ba[n/2] (pa), odd -> bi[n/2] (pi)
  float bias[4];
#pragma unroll
  for (int j = 0; j < 4; ++j) {
    const int n = nBase + wn + j * 16 + lrow;
    bias[j] = (n & 1) ? bi[n >> 1] : ba[n >> 1];
  }

  // gate-phase thread roles: col = i-lane 0..63, q = s-quarter (16 rows each)
  const int col = t & 63;
  const int q = t >> 6;
  const float alpha = sigmoidf_(gate[(nBase >> 1) + col]);
  const int b = blockIdx.y >> 4;  // 16 m-tiles per batch

  // 2 rounds of 64 m-rows: stage C+bias -> LDS, compute a,c, store AC, local scan.
  // C/D layout: col = lane&15, row = quad*4 + reg (m89-verified)
#pragma unroll
  for (int h = 0; h < 2; ++h) {
    if (wm == h * 64) {
#pragma unroll
      for (int i = 0; i < 4; ++i)
#pragma unroll
        for (int j = 0; j < 4; ++j)
#pragma unroll
          for (int rr = 0; rr < 4; ++rr)
            smem[(i * 16 + quad * 4 + rr) * 136 + wn + j * 16 + lrow] =
                (_Float16)(acc[i][j][rr] + bias[j]);
    }
    __syncthreads();
    float A = 1.0f, Hn = 0.0f;
    _Float16* ACp = AC + (size_t)(mBase + h * 64 + q * 16) * N2 + nBase + 2 * col;
#pragma unroll 4
    for (int rs = 0; rs < 16; ++rs) {
      f16x2 pp = *(const f16x2*)(smem + (q * 16 + rs) * 136 + 2 * col);
      float a, c;
      gate_ac((float)pp[0], (float)pp[1], alpha, a, c);
      f16x2 o;
      o[0] = (_Float16)a;
      o[1] = (_Float16)c;
      *(f16x2*)ACp = o;
      ACp += N2;
      A *= a;
      Hn = fmaf(a, Hn, c);
    }
    pAs[(h * 4 + q) * 65 + col] = A;
    pHs[(h * 4 + q) * 65 + col] = Hn;
    __syncthreads();
  }

  // combine 8x16-step partials -> 4x32-step aggregates (s-ascending pairs)
  if (t < 64) {
#pragma unroll
    for (int k = 0; k < 4; ++k) {
      float A0 = pAs[(2 * k) * 65 + t], H0 = pHs[(2 * k) * 65 + t];
      float A1 = pAs[(2 * k + 1) * 65 + t], H1 = pHs[(2 * k + 1) * 65 + t];
      const int ch = ((blockIdx.y & 15) << 2) + k;
      agg[((size_t)(b * 64 + ch)) * 2048 + (nBase >> 1) + t] =
          make_float2(A0 * A1, fmaf(A1, H0, H1));
    }
  }
}

__global__ __launch_bounds__(64) void scan_pass2(const float2* __restrict__ agg,
                                                 float* __restrict__ carry) {
  const int i = blockIdx.x * 64 + threadIdx.x;  // grid.x=32 -> 0..2047
  const int b = blockIdx.y;
  float h = 0.0f;
  for (int c8 = 0; c8 < 8; ++c8) {
    float2 aH[8];
#pragma unroll
    for (int u = 0; u < 8; ++u)
      aH[u] = agg[((size_t)(b * 64 + c8 * 8 + u)) * 2048 + i];
#pragma unroll
    for (int u = 0; u < 8; ++u) {
      carry[((size_t)(b * 64 + c8 * 8 + u)) * 2048 + i] = h;
      h = fmaf(aH[u].x, h, aH[u].y);
    }
  }
}

// Pure fma replay: h = a*h + c, no transcendentals.
__global__ __launch_bounds__(256) void scan_out(const _Float16* __restrict__ AC,
                                                const float* __restrict__ carry,
                                                float* __restrict__ out) {
  const int tt = blockIdx.x * 256 + threadIdx.x;  // 0..1023 (2 i's per thread)
  const int i0 = tt * 2;
  const int ch = blockIdx.y;  // 0..63
  const int b = blockIdx.z;
  const float2 cr = ((const float2*)(carry + ((size_t)(b * 64 + ch)) * 2048))[tt];
  float h0 = cr.x, h1 = cr.y;
  const _Float16* row = AC + ((size_t)(b * 2048 + ch * 32)) * 4096 + i0 * 2;
  float* orow = out + ((size_t)(b * 2048 + ch * 32)) * 2048 + i0;
  for (int s4 = 0; s4 < 8; ++s4) {
    f16x4 v[4];
#pragma unroll
    for (int u = 0; u < 4; ++u)
      v[u] = *(const f16x4*)(row + (size_t)u * 4096);
    row += 4 * 4096;
#pragma unroll
    for (int u = 0; u < 4; ++u) {
      h0 = fmaf((float)v[u][0], h0, (float)v[u][1]);
      h1 = fmaf((float)v[u][2], h1, (float)v[u][3]);
      float2 o;
      o.x = h0;
      o.y = h1;
      *(float2*)(orow + (size_t)u * 2048) = o;
    }
    orow += 4 * 2048;
  }
}

extern "C" void kernel_launch(void* const* d_in, const int* in_sizes, int n_in,
                              void* d_out, int out_size, void* d_ws, size_t ws_size,
                              hipStream_t stream) {
  const float* x = (const float*)d_in[0];
  const float* Wa = (const float*)d_in[1];
  const float* ba = (const float*)d_in[2];
  const float* Wi = (const float*)d_in[3];
  const float* bi = (const float*)d_in[4];
  const float* gate = (const float*)d_in[5];
  float* out = (float*)d_out;

  char* ws = (char*)d_ws;
  _Float16* xh = (_Float16*)ws;               // 16 MiB
  _Float16* wh = (_Float16*)(ws + 16777216);  // 4 MiB (interleaved Wa/Wi)
  const size_t MN2 = (size_t)16384 * 4096;
  _Float16* AC = (_Float16*)(ws + 20971520);  // 128 MiB fp16 (a,c) interleaved
  float2* agg = (float2*)(ws + 20971520 + MN2 * 2);            // 8 MiB
  float* carry = (float*)(ws + 20971520 + MN2 * 2 + 8388608);  // 4 MiB

  cvt_all<<<10240, 256, 0, stream>>>(x, Wa, Wi, xh, wh);
  gemm_gate<<<dim3(32, 128), 256, 0, stream>>>(xh, wh, ba, bi, gate, AC, agg);
  scan_pass2<<<dim3(32, 8), 64, 0, stream>>>(agg, carry);
  scan_out<<<dim3(4, 64, 8), 256, 0, stream>>>(AC, carry, out);
}